// Round 2
// baseline (100.752 us; speedup 1.0000x reference)
//
#include <hip/hip_runtime.h>
#include <math.h>

// Problem constants
#define TT 32
#define BB 16
#define DD 128
#define MAT 16384            // D*D
// Workspace float offsets
#define OFF_MR   0
#define OFF_MI   16384
#define OFF_YTR  32768                    // 64 * 16384
#define OFF_YTI  (32768 + 64*16384)       // 1081344
#define OFF_ZSR  (OFF_YTI + 64*16384)     // 2129920 : Zs = Z^T, [kk*16+b][i][j]
#define OFF_ZSI  (OFF_ZSR + 32*16384)
#define OFF_VR   (OFF_ZSI + 32*16384)     // V natural [t*16+b][i][j]
#define OFF_VI   (OFF_VR + 32*16384)
#define OFF_TR   (OFF_VI + 32*16384)      // tr[q][kk][b][2]
#define OFF_S    (OFF_TR + 2048)          // s[q][kk][b]

__device__ __forceinline__ float dot4(float4 a, float4 b) {
    return a.x*b.x + a.y*b.y + a.z*b.z + a.w*b.w;
}

// ---------------- Kernel 1: M = Uq^H * Uk  (complex 128x128) ----------------
__global__ __launch_bounds__(128) void k_M(const float* __restrict__ Uq,
                                           const float* __restrict__ Uk,
                                           float* __restrict__ ws) {
    const int i = blockIdx.x;
    const int j = threadIdx.x;
    __shared__ float qr_s[128], qi_s[128];
    qr_s[j] = Uq[(j*128 + i)*2 + 0];   // Uq[p=j, i]
    qi_s[j] = Uq[(j*128 + i)*2 + 1];
    __syncthreads();
    const float2* Uk2 = (const float2*)Uk;
    float mr = 0.f, mi = 0.f;
    #pragma unroll 8
    for (int p = 0; p < 128; ++p) {
        float2 k2 = Uk2[p*128 + j];
        float qr = qr_s[p], qi = qi_s[p];
        mr += qr*k2.x + qi*k2.y;       // conj(Uq[p,i]) * Uk[p,j]
        mi += qr*k2.y - qi*k2.x;
    }
    ws[OFF_MR + i*128 + j] = mr;
    ws[OFF_MI + i*128 + j] = mi;
}

// ---------------- Kernel 2: batched 32-row-strip complex GEMM ----------------
// STAGE 0: OUT = U * X          (U = M for m<32, Uv for m>=32); store OUT^T -> YT
// STAGE 1: OUT = conj(U) * YT;  m<32: natural store -> Zs (= Z^T); m>=32: store OUT^T -> V
template<int STAGE>
__global__ __launch_bounds__(256) void k_evolve(const float* __restrict__ xr,
                                                const float* __restrict__ xi,
                                                const float* __restrict__ Uv,
                                                float* __restrict__ ws) {
    const int bid = blockIdx.x;
    const int m   = bid >> 2;            // 0..63
    const int i0  = (bid & 3) * 32;      // row strip
    const int tid = threadIdx.x;
    const int rp  = tid >> 4;            // 0..15 row pair
    const int jg  = tid & 15;            // 0..15 col group; cols = jg*4 + 64*s + q

    __shared__ float Bt_r[16][128], Bt_i[16][128];
    __shared__ float At_r[32][17],  At_i[32][17];
    __shared__ float T_r[32][129],  T_i[32][129];

    float accr[2][8], acci[2][8];
    #pragma unroll
    for (int r = 0; r < 2; ++r)
        #pragma unroll
        for (int k = 0; k < 8; ++k) { accr[r][k] = 0.f; acci[r][k] = 0.f; }

    const float* Br;
    const float* Bi;
    if (STAGE == 0) { Br = xr + (m & 31) * MAT;      Bi = xi + (m & 31) * MAT; }
    else            { Br = ws + OFF_YTR + m * MAT;   Bi = ws + OFF_YTI + m * MAT; }

    for (int p0 = 0; p0 < 128; p0 += 16) {
        __syncthreads();
        // B tile: rows p0..p0+15, all 128 cols (float4 loads)
        #pragma unroll
        for (int w = 0; w < 2; ++w) {
            int l = w*256 + tid;            // float4 index 0..511
            int row = l >> 5, c4 = l & 31;
            ((float4*)Bt_r[row])[c4] = ((const float4*)Br)[(p0+row)*32 + c4];
            ((float4*)Bt_i[row])[c4] = ((const float4*)Bi)[(p0+row)*32 + c4];
        }
        // A tile: U rows i0..i0+31, cols p0..p0+15
        #pragma unroll
        for (int w = 0; w < 2; ++w) {
            int l = w*256 + tid;            // 0..511
            int r = l >> 4, pp = l & 15;
            float ar, ai;
            if (m < 32) {
                ar = ws[OFF_MR + (i0+r)*128 + p0 + pp];
                ai = ws[OFF_MI + (i0+r)*128 + p0 + pp];
            } else {
                float2 u = ((const float2*)Uv)[(i0+r)*128 + p0 + pp];
                ar = u.x; ai = u.y;
            }
            At_r[r][pp] = ar; At_i[r][pp] = ai;
        }
        __syncthreads();
        #pragma unroll
        for (int pp = 0; pp < 16; ++pp) {
            const float ar0 = At_r[2*rp+0][pp], ai0 = At_i[2*rp+0][pp];
            const float ar1 = At_r[2*rp+1][pp], ai1 = At_i[2*rp+1][pp];
            const float4* br4 = (const float4*)(&Bt_r[pp][0]);
            const float4* bi4 = (const float4*)(&Bt_i[pp][0]);
#define CF(R, K, BR, BI)                                                        \
    do {                                                                        \
        const float aR_ = (R) ? ar1 : ar0; const float aI_ = (R) ? ai1 : ai0;   \
        if (STAGE == 0) { accr[R][K] += aR_*(BR) - aI_*(BI);                    \
                          acci[R][K] += aR_*(BI) + aI_*(BR); }                  \
        else            { accr[R][K] += aR_*(BR) + aI_*(BI);                    \
                          acci[R][K] += aR_*(BI) - aI_*(BR); }                  \
    } while (0)
            #pragma unroll
            for (int s = 0; s < 2; ++s) {
                const float4 brv = br4[jg + 16*s];
                const float4 biv = bi4[jg + 16*s];
                CF(0, s*4+0, brv.x, biv.x); CF(0, s*4+1, brv.y, biv.y);
                CF(0, s*4+2, brv.z, biv.z); CF(0, s*4+3, brv.w, biv.w);
                CF(1, s*4+0, brv.x, biv.x); CF(1, s*4+1, brv.y, biv.y);
                CF(1, s*4+2, brv.z, biv.z); CF(1, s*4+3, brv.w, biv.w);
            }
#undef CF
        }
    }

    const bool transpose_store = (STAGE == 0) || (m >= 32);
    if (transpose_store) {
        __syncthreads();
        #pragma unroll
        for (int r = 0; r < 2; ++r)
            #pragma unroll
            for (int s = 0; s < 2; ++s)
                #pragma unroll
                for (int q = 0; q < 4; ++q) {
                    T_r[2*rp+r][jg*4 + 64*s + q] = accr[r][s*4+q];
                    T_i[2*rp+r][jg*4 + 64*s + q] = acci[r][s*4+q];
                }
        __syncthreads();
        float* dstR; float* dstI;
        if (STAGE == 0) { dstR = ws + OFF_YTR + m*MAT;      dstI = ws + OFF_YTI + m*MAT; }
        else            { dstR = ws + OFF_VR + (m-32)*MAT;  dstI = ws + OFF_VI + (m-32)*MAT; }
        #pragma unroll
        for (int w = 0; w < 16; ++w) {
            int o = w*256 + tid;
            int c = o >> 5, ii = o & 31;
            dstR[c*128 + i0 + ii] = T_r[ii][c];
            dstI[c*128 + i0 + ii] = T_i[ii][c];
        }
    } else {
        float* dstR = ws + OFF_ZSR + m*MAT;
        float* dstI = ws + OFF_ZSI + m*MAT;
        #pragma unroll
        for (int r = 0; r < 2; ++r)
            #pragma unroll
            for (int s = 0; s < 2; ++s) {
                float4 vR = make_float4(accr[r][s*4+0], accr[r][s*4+1], accr[r][s*4+2], accr[r][s*4+3]);
                float4 vI = make_float4(acci[r][s*4+0], acci[r][s*4+1], acci[r][s*4+2], acci[r][s*4+3]);
                *(float4*)&dstR[(i0 + 2*rp + r)*128 + jg*4 + 64*s] = vR;
                *(float4*)&dstI[(i0 + 2*rp + r)*128 + jg*4 + 64*s] = vI;
            }
    }
}

// ---------------- Kernel 3: tr[q,kk,b] = sum X_qb .* Zs_kkb (complex) ----------------
__global__ __launch_bounds__(256) void k_trace(const float* __restrict__ xr,
                                               const float* __restrict__ xi,
                                               float* __restrict__ ws) {
    const int q = blockIdx.x >> 4, b = blockIdx.x & 15;
    const int tid = threadIdx.x;
    const float4* Xr4  = (const float4*)(xr + (q*16 + b)*MAT);
    const float4* Xi4  = (const float4*)(xi + (q*16 + b)*MAT);
    const float4* Z0r4 = (const float4*)(ws + OFF_ZSR + b*MAT);
    const float4* Z0i4 = (const float4*)(ws + OFF_ZSI + b*MAT);
    const float4* Z1r4 = (const float4*)(ws + OFF_ZSR + (16+b)*MAT);
    const float4* Z1i4 = (const float4*)(ws + OFF_ZSI + (16+b)*MAT);
    float r0 = 0.f, s0 = 0.f, r1 = 0.f, s1 = 0.f;
    #pragma unroll 4
    for (int w = 0; w < 16; ++w) {
        int e = w*256 + tid;
        float4 xrv = Xr4[e], xiv = Xi4[e];
        float4 z0r = Z0r4[e], z0i = Z0i4[e];
        float4 z1r = Z1r4[e], z1i = Z1i4[e];
        r0 += dot4(xrv, z0r) - dot4(xiv, z0i);
        s0 += dot4(xrv, z0i) + dot4(xiv, z0r);
        r1 += dot4(xrv, z1r) - dot4(xiv, z1i);
        s1 += dot4(xrv, z1i) + dot4(xiv, z1r);
    }
    #pragma unroll
    for (int off = 32; off > 0; off >>= 1) {
        r0 += __shfl_down(r0, off);
        s0 += __shfl_down(s0, off);
        r1 += __shfl_down(r1, off);
        s1 += __shfl_down(s1, off);
    }
    __shared__ float red[4][4];
    if ((tid & 63) == 0) {
        int wv = tid >> 6;
        red[wv][0] = r0; red[wv][1] = s0; red[wv][2] = r1; red[wv][3] = s1;
    }
    __syncthreads();
    if (tid == 0) {
        float a0 = red[0][0]+red[1][0]+red[2][0]+red[3][0];
        float a1 = red[0][1]+red[1][1]+red[2][1]+red[3][1];
        float a2 = red[0][2]+red[1][2]+red[2][2]+red[3][2];
        float a3 = red[0][3]+red[1][3]+red[2][3]+red[3][3];
        float* trp = ws + OFF_TR;
        trp[((q*2+0)*16 + b)*2 + 0] = a0;
        trp[((q*2+0)*16 + b)*2 + 1] = a1;
        trp[((q*2+1)*16 + b)*2 + 0] = a2;
        trp[((q*2+1)*16 + b)*2 + 1] = a3;
    }
}

// ---------------- Kernel 4: softmax over b for (q,kk) ----------------
__global__ __launch_bounds__(64) void k_softmax(float* __restrict__ ws) {
    const int t = threadIdx.x;      // 0..63 -> (q,kk)
    const float* trp = ws + OFF_TR + t*32;   // 16 b * 2
    float d[16];
    float mx = -1e30f;
    #pragma unroll
    for (int b = 0; b < 16; ++b) {
        float rr = trp[b*2+0], ii = trp[b*2+1];
        d[b] = sqrtf(rr*rr + ii*ii);
        mx = fmaxf(mx, d[b]);
    }
    float sum = 0.f;
    #pragma unroll
    for (int b = 0; b < 16; ++b) { d[b] = expf(d[b] - mx); sum += d[b]; }
    float inv = 1.f / sum;
    #pragma unroll
    for (int b = 0; b < 16; ++b) ws[OFF_S + t*16 + b] = d[b] * inv;
}

// ---------------- Kernel 5: broadcast output ----------------
__global__ __launch_bounds__(256) void k_out(const float* __restrict__ ws,
                                             float* __restrict__ out) {
    const int t = blockIdx.x >> 4, b = blockIdx.x & 15;
    const float s0 = ws[OFF_S + (t*2+0)*16 + b];
    const float s1 = ws[OFF_S + (t*2+1)*16 + b];
    const float4* Vr0 = (const float4*)(ws + OFF_VR + b*MAT);
    const float4* Vi0 = (const float4*)(ws + OFF_VI + b*MAT);
    const float4* Vr1 = (const float4*)(ws + OFF_VR + (16+b)*MAT);
    const float4* Vi1 = (const float4*)(ws + OFF_VI + (16+b)*MAT);
    float4* outR = (float4*)out + (t*16 + b)*4096;
    float4* outI = (float4*)out + 2097152 + (t*16 + b)*4096;
    #pragma unroll 4
    for (int w = 0; w < 16; ++w) {
        int e = w*256 + threadIdx.x;
        float4 a = Vr0[e], bb = Vi0[e], c = Vr1[e], dd = Vi1[e];
        outR[e] = make_float4(a.x*s0 + bb.x*s1, a.y*s0 + bb.y*s1,
                              a.z*s0 + bb.z*s1, a.w*s0 + bb.w*s1);
        outI[e] = make_float4(c.x*s0 + dd.x*s1, c.y*s0 + dd.y*s1,
                              c.z*s0 + dd.z*s1, c.w*s0 + dd.w*s1);
    }
}

extern "C" void kernel_launch(void* const* d_in, const int* in_sizes, int n_in,
                              void* d_out, int out_size, void* d_ws, size_t ws_size,
                              hipStream_t stream) {
    const float* xr = (const float*)d_in[0];
    const float* xi = (const float*)d_in[1];
    const float* Uq = (const float*)d_in[2];
    const float* Uk = (const float*)d_in[3];
    const float* Uv = (const float*)d_in[4];
    float* ws  = (float*)d_ws;
    float* out = (float*)d_out;

    k_M<<<128, 128, 0, stream>>>(Uq, Uk, ws);
    k_evolve<0><<<256, 256, 0, stream>>>(xr, xi, Uv, ws);
    k_evolve<1><<<256, 256, 0, stream>>>(xr, xi, Uv, ws);
    k_trace<<<512, 256, 0, stream>>>(xr, xi, ws);
    k_softmax<<<1, 64, 0, stream>>>(ws);
    k_out<<<512, 256, 0, stream>>>(ws, out);
}

// Round 3
// 92.315 us; speedup vs baseline: 1.0914x; 1.0914x over previous
//
#include <hip/hip_runtime.h>
#include <math.h>

// Problem constants
#define TT 32
#define BB 16
#define DD 128
#define MAT 16384            // D*D
// Workspace float offsets (≈17.2 MB total, unchanged from passing version)
#define OFF_MR   0
#define OFF_MI   16384
#define OFF_YTR  32768                    // 64 * 16384
#define OFF_YTI  (32768 + 64*16384)       // 1081344
#define OFF_ZSR  (OFF_YTI + 64*16384)     // 2129920 : Zs = Z^T, [kk*16+b][i][j]
#define OFF_ZSI  (OFF_ZSR + 32*16384)
#define OFF_VR   (OFF_ZSI + 32*16384)     // V natural [t*16+b][i][j]
#define OFF_VI   (OFF_VR + 32*16384)
#define OFF_TR   (OFF_VI + 32*16384)      // tr[q][kk][b][2]
#define OFF_S    (OFF_TR + 2048)          // s[q][kk][b]

__device__ __forceinline__ float dot4(float4 a, float4 b) {
    return a.x*b.x + a.y*b.y + a.z*b.z + a.w*b.w;
}

// ---------------- Kernel 1: M = Uq^H * Uk  (complex 128x128) ----------------
__global__ __launch_bounds__(128) void k_M(const float* __restrict__ Uq,
                                           const float* __restrict__ Uk,
                                           float* __restrict__ ws) {
    const int i = blockIdx.x;
    const int j = threadIdx.x;
    __shared__ float qr_s[128], qi_s[128];
    qr_s[j] = Uq[(j*128 + i)*2 + 0];   // Uq[p=j, i]
    qi_s[j] = Uq[(j*128 + i)*2 + 1];
    __syncthreads();
    const float2* Uk2 = (const float2*)Uk;
    float mr = 0.f, mi = 0.f;
    #pragma unroll 8
    for (int p = 0; p < 128; ++p) {
        float2 k2 = Uk2[p*128 + j];
        float qr = qr_s[p], qi = qi_s[p];
        mr += qr*k2.x + qi*k2.y;       // conj(Uq[p,i]) * Uk[p,j]
        mi += qr*k2.y - qi*k2.x;
    }
    ws[OFF_MR + i*128 + j] = mr;
    ws[OFF_MI + i*128 + j] = mi;
}

// ---------------- Kernel 2: batched 32-row-strip complex GEMM (v2) ----------------
// grid 256: bid -> m (0..63), strip i0 = (bid&3)*32. 256 threads.
// Thread tile: 4 rows x 4 cols. A-strip preloaded to LDS transposed [p][row]
// (two K-halves). B tile double-buffered: gload t+1 -> regs during compute t.
// STAGE 0: OUT = U * X          (U = M for m<32, Uv for m>=32); store OUT^T -> YT
// STAGE 1: OUT = conj(U) * YT;  m<32: natural store -> Zs (= Z^T); m>=32: OUT^T -> V
#define AT_PAD 36            // floats per [p] row of At (32 rows + pad, 144B: 16B-aligned)
template<int STAGE>
__global__ __launch_bounds__(256) void k_evolve(const float* __restrict__ xr,
                                                const float* __restrict__ xi,
                                                const float* __restrict__ Uv,
                                                float* __restrict__ ws) {
    const int bid = blockIdx.x;
    const int m   = bid >> 2;            // 0..63
    const int i0  = (bid & 3) * 32;      // row strip
    const int tid = threadIdx.x;
    const int rg  = tid >> 5;            // 0..7  -> rows i0 + rg*4 + r
    const int cg  = tid & 31;            // 0..31 -> cols cg*4 + k

    // LDS: At re/im [64][AT_PAD] (2304 floats each) + B double buffer 2x(re 2048 + im 2048)
    __shared__ __align__(16) float smem_f[2304*2 + 4096*2];   // 51200 B
    float* At_r = smem_f;
    float* At_i = smem_f + 2304;
    float* Bbuf = smem_f + 4608;
    // Epilogue transpose buffer aliases the front of smem (At + part of B; both dead then)
    float* T_r = smem_f;                 // [32][129]
    float* T_i = smem_f + 32*129;

    float accr[4][4], acci[4][4];
    #pragma unroll
    for (int r = 0; r < 4; ++r)
        #pragma unroll
        for (int k = 0; k < 4; ++k) { accr[r][k] = 0.f; acci[r][k] = 0.f; }

    const float* Br;
    const float* Bi;
    if (STAGE == 0) { Br = xr + (m & 31) * MAT;      Bi = xi + (m & 31) * MAT; }
    else            { Br = ws + OFF_YTR + m * MAT;   Bi = ws + OFF_YTI + m * MAT; }
    const float4* Br4 = (const float4*)Br;
    const float4* Bi4 = (const float4*)Bi;

    // ---- A-strip half loader: rows i0..i0+31, p in [h*64, h*64+64) -> At[p][r] ----
    auto loadA = [&](int h) {
        #pragma unroll
        for (int w = 0; w < 8; ++w) {
            int idx = w*256 + tid;       // 0..2047
            int r = idx >> 6;            // 0..31
            int p = idx & 63;            // 0..63
            float ar, ai;
            if (m < 32) {
                ar = ws[OFF_MR + (i0+r)*128 + h*64 + p];
                ai = ws[OFF_MI + (i0+r)*128 + h*64 + p];
            } else {
                float2 u = ((const float2*)Uv)[(i0+r)*128 + h*64 + p];
                ar = u.x; ai = u.y;
            }
            At_r[p*AT_PAD + r] = ar;
            At_i[p*AT_PAD + r] = ai;
        }
    };

    // ---- B tile gload (tile t: rows t*16..t*16+15, all 128 cols) into regs ----
    float4 pr0, pr1, pi0, pi1;
    auto gloadB = [&](int t) {
        int b0 = t*512;                  // float4 base (16 rows * 32 f4)
        pr0 = Br4[b0 + tid];
        pr1 = Br4[b0 + 256 + tid];
        pi0 = Bi4[b0 + tid];
        pi1 = Bi4[b0 + 256 + tid];
    };
    auto writeB = [&](int buf) {
        float4* dR = (float4*)(Bbuf + buf*4096);
        float4* dI = (float4*)(Bbuf + buf*4096 + 2048);
        dR[tid]       = pr0;
        dR[tid + 256] = pr1;
        dI[tid]       = pi0;
        dI[tid + 256] = pi1;
    };

    loadA(0);
    gloadB(0);
    writeB(0);

    for (int t = 0; t < 8; ++t) {
        if (t < 7) gloadB(t+1);          // in flight during compute of tile t
        __syncthreads();                  // buf[t&1] + (At half) visible
        if (t == 4) { loadA(1); __syncthreads(); }
        const float* bufR = Bbuf + (t&1)*4096;
        const float* bufI = bufR + 2048;
        #pragma unroll
        for (int pp = 0; pp < 16; ++pp) {
            const int pl = ((t & 3) << 4) + pp;     // p within current A half
            const float4 ar4 = *(const float4*)&At_r[pl*AT_PAD + (rg<<2)];
            const float4 ai4 = *(const float4*)&At_i[pl*AT_PAD + (rg<<2)];
            const float4 brv = *(const float4*)&bufR[pp*128 + (cg<<2)];
            const float4 biv = *(const float4*)&bufI[pp*128 + (cg<<2)];
#define CROW(R, AR, AI)                                                          \
    do {                                                                         \
        const float aR_ = (AR), aI_ = (AI);                                      \
        const float br_[4] = {brv.x, brv.y, brv.z, brv.w};                       \
        const float bi_[4] = {biv.x, biv.y, biv.z, biv.w};                       \
        _Pragma("unroll")                                                        \
        for (int k = 0; k < 4; ++k) {                                            \
            if (STAGE == 0) { accr[R][k] += aR_*br_[k] - aI_*bi_[k];             \
                              acci[R][k] += aR_*bi_[k] + aI_*br_[k]; }           \
            else            { accr[R][k] += aR_*br_[k] + aI_*bi_[k];             \
                              acci[R][k] += aR_*bi_[k] - aI_*br_[k]; }           \
        }                                                                        \
    } while (0)
            CROW(0, ar4.x, ai4.x);
            CROW(1, ar4.y, ai4.y);
            CROW(2, ar4.z, ai4.z);
            CROW(3, ar4.w, ai4.w);
#undef CROW
        }
        if (t < 7) writeB((t+1)&1);
    }

    const bool transpose_store = (STAGE == 0) || (m >= 32);
    if (transpose_store) {
        __syncthreads();                  // everyone done with At/Bbuf
        #pragma unroll
        for (int r = 0; r < 4; ++r)
            #pragma unroll
            for (int k = 0; k < 4; ++k) {
                T_r[((rg<<2)+r)*129 + (cg<<2)+k] = accr[r][k];
                T_i[((rg<<2)+r)*129 + (cg<<2)+k] = acci[r][k];
            }
        __syncthreads();
        float* dstR; float* dstI;
        if (STAGE == 0) { dstR = ws + OFF_YTR + m*MAT;      dstI = ws + OFF_YTI + m*MAT; }
        else            { dstR = ws + OFF_VR + (m-32)*MAT;  dstI = ws + OFF_VI + (m-32)*MAT; }
        #pragma unroll
        for (int w = 0; w < 16; ++w) {
            int o = w*256 + tid;
            int c = o >> 5, ii = o & 31;
            dstR[c*128 + i0 + ii] = T_r[ii*129 + c];
            dstI[c*128 + i0 + ii] = T_i[ii*129 + c];
        }
    } else {
        float* dstR = ws + OFF_ZSR + m*MAT;
        float* dstI = ws + OFF_ZSI + m*MAT;
        #pragma unroll
        for (int r = 0; r < 4; ++r) {
            float4 vR = make_float4(accr[r][0], accr[r][1], accr[r][2], accr[r][3]);
            float4 vI = make_float4(acci[r][0], acci[r][1], acci[r][2], acci[r][3]);
            *(float4*)&dstR[(i0 + (rg<<2) + r)*128 + (cg<<2)] = vR;
            *(float4*)&dstI[(i0 + (rg<<2) + r)*128 + (cg<<2)] = vI;
        }
    }
}

// ---------------- Kernel 3: tr[q,kk,b] = sum X_qb .* Zs_kkb (complex) ----------------
__global__ __launch_bounds__(256) void k_trace(const float* __restrict__ xr,
                                               const float* __restrict__ xi,
                                               float* __restrict__ ws) {
    const int q = blockIdx.x >> 4, b = blockIdx.x & 15;
    const int tid = threadIdx.x;
    const float4* Xr4  = (const float4*)(xr + (q*16 + b)*MAT);
    const float4* Xi4  = (const float4*)(xi + (q*16 + b)*MAT);
    const float4* Z0r4 = (const float4*)(ws + OFF_ZSR + b*MAT);
    const float4* Z0i4 = (const float4*)(ws + OFF_ZSI + b*MAT);
    const float4* Z1r4 = (const float4*)(ws + OFF_ZSR + (16+b)*MAT);
    const float4* Z1i4 = (const float4*)(ws + OFF_ZSI + (16+b)*MAT);
    float r0 = 0.f, s0 = 0.f, r1 = 0.f, s1 = 0.f;
    #pragma unroll 4
    for (int w = 0; w < 16; ++w) {
        int e = w*256 + tid;
        float4 xrv = Xr4[e], xiv = Xi4[e];
        float4 z0r = Z0r4[e], z0i = Z0i4[e];
        float4 z1r = Z1r4[e], z1i = Z1i4[e];
        r0 += dot4(xrv, z0r) - dot4(xiv, z0i);
        s0 += dot4(xrv, z0i) + dot4(xiv, z0r);
        r1 += dot4(xrv, z1r) - dot4(xiv, z1i);
        s1 += dot4(xrv, z1i) + dot4(xiv, z1r);
    }
    #pragma unroll
    for (int off = 32; off > 0; off >>= 1) {
        r0 += __shfl_down(r0, off);
        s0 += __shfl_down(s0, off);
        r1 += __shfl_down(r1, off);
        s1 += __shfl_down(s1, off);
    }
    __shared__ float red[4][4];
    if ((tid & 63) == 0) {
        int wv = tid >> 6;
        red[wv][0] = r0; red[wv][1] = s0; red[wv][2] = r1; red[wv][3] = s1;
    }
    __syncthreads();
    if (tid == 0) {
        float a0 = red[0][0]+red[1][0]+red[2][0]+red[3][0];
        float a1 = red[0][1]+red[1][1]+red[2][1]+red[3][1];
        float a2 = red[0][2]+red[1][2]+red[2][2]+red[3][2];
        float a3 = red[0][3]+red[1][3]+red[2][3]+red[3][3];
        float* trp = ws + OFF_TR;
        trp[((q*2+0)*16 + b)*2 + 0] = a0;
        trp[((q*2+0)*16 + b)*2 + 1] = a1;
        trp[((q*2+1)*16 + b)*2 + 0] = a2;
        trp[((q*2+1)*16 + b)*2 + 1] = a3;
    }
}

// ---------------- Kernel 4: softmax over b for (q,kk) ----------------
__global__ __launch_bounds__(64) void k_softmax(float* __restrict__ ws) {
    const int t = threadIdx.x;      // 0..63 -> (q,kk)
    const float* trp = ws + OFF_TR + t*32;   // 16 b * 2
    float d[16];
    float mx = -1e30f;
    #pragma unroll
    for (int b = 0; b < 16; ++b) {
        float rr = trp[b*2+0], ii = trp[b*2+1];
        d[b] = sqrtf(rr*rr + ii*ii);
        mx = fmaxf(mx, d[b]);
    }
    float sum = 0.f;
    #pragma unroll
    for (int b = 0; b < 16; ++b) { d[b] = expf(d[b] - mx); sum += d[b]; }
    float inv = 1.f / sum;
    #pragma unroll
    for (int b = 0; b < 16; ++b) ws[OFF_S + t*16 + b] = d[b] * inv;
}

// ---------------- Kernel 5: broadcast output ----------------
__global__ __launch_bounds__(256) void k_out(const float* __restrict__ ws,
                                             float* __restrict__ out) {
    const int t = blockIdx.x >> 4, b = blockIdx.x & 15;
    const float s0 = ws[OFF_S + (t*2+0)*16 + b];
    const float s1 = ws[OFF_S + (t*2+1)*16 + b];
    const float4* Vr0 = (const float4*)(ws + OFF_VR + b*MAT);
    const float4* Vi0 = (const float4*)(ws + OFF_VI + b*MAT);
    const float4* Vr1 = (const float4*)(ws + OFF_VR + (16+b)*MAT);
    const float4* Vi1 = (const float4*)(ws + OFF_VI + (16+b)*MAT);
    float4* outR = (float4*)out + (t*16 + b)*4096;
    float4* outI = (float4*)out + 2097152 + (t*16 + b)*4096;
    #pragma unroll 4
    for (int w = 0; w < 16; ++w) {
        int e = w*256 + threadIdx.x;
        float4 a = Vr0[e], bb = Vi0[e], c = Vr1[e], dd = Vi1[e];
        outR[e] = make_float4(a.x*s0 + bb.x*s1, a.y*s0 + bb.y*s1,
                              a.z*s0 + bb.z*s1, a.w*s0 + bb.w*s1);
        outI[e] = make_float4(c.x*s0 + dd.x*s1, c.y*s0 + dd.y*s1,
                              c.z*s0 + dd.z*s1, c.w*s0 + dd.w*s1);
    }
}

extern "C" void kernel_launch(void* const* d_in, const int* in_sizes, int n_in,
                              void* d_out, int out_size, void* d_ws, size_t ws_size,
                              hipStream_t stream) {
    const float* xr = (const float*)d_in[0];
    const float* xi = (const float*)d_in[1];
    const float* Uq = (const float*)d_in[2];
    const float* Uk = (const float*)d_in[3];
    const float* Uv = (const float*)d_in[4];
    float* ws  = (float*)d_ws;
    float* out = (float*)d_out;

    k_M<<<128, 128, 0, stream>>>(Uq, Uk, ws);
    k_evolve<0><<<256, 256, 0, stream>>>(xr, xi, Uv, ws);
    k_evolve<1><<<256, 256, 0, stream>>>(xr, xi, Uv, ws);
    k_trace<<<512, 256, 0, stream>>>(xr, xi, ws);
    k_softmax<<<1, 64, 0, stream>>>(ws);
    k_out<<<512, 256, 0, stream>>>(ws, out);
}